// Round 11
// baseline (74.963 us; speedup 1.0000x reference)
//
#include <hip/hip_runtime.h>

// R11: zero-barrier, fully per-wave-decoupled fused conv+MLP.
//   Each wave owns 16 rows end-to-end: bulk-copy own x rows (fp32->bf16,
//   12-deep pinned load batches), private LDS tile, GEMM1 (A from LDS,
//   B reg-prefetched d1 from L2-resident weff), h1/h2 in LDS (own rows),
//   GEMM2/3, store. NO __syncthreads anywhere; waves drift so copy and
//   compute overlap across waves/blocks statistically, not by schedule.
//   BM=32, NT=128 (2 waves), 1024 blocks, LDS 71,168 B -> 2 blocks/CU.
//   __launch_bounds__(128,1): ~500-VGPR budget -> no spill (R5 disease).

typedef __attribute__((ext_vector_type(8))) short bf16x8;
typedef __attribute__((ext_vector_type(4))) float f32x4;

#define KP1 832     // Weff K padded (784 -> 13*64)
#define NP  112
#define K2P 128
#define BM  32
#define NT  128
#define XC  840     // ushorts per xb row (832 used + 8; stride 420 words)

#define W2T_OFF (NP * KP1)              // 93184
#define W3T_OFF (W2T_OFF + NP * K2P)    // 107520

#define SBAR0 __builtin_amdgcn_sched_barrier(0)

__device__ __forceinline__ unsigned short f2bf(float f) {
    unsigned int u = __float_as_uint(f);
    u += 0x7FFFu + ((u >> 16) & 1u);    // RNE
    return (unsigned short)(u >> 16);
}

__device__ __forceinline__ unsigned int pkbf(float a, float b) {
    unsigned int r;
    asm("v_cvt_pk_bf16_f32 %0, %1, %2" : "=v"(r) : "v"(a), "v"(b));
    return r;
}

// ---------------- Kernel A: weights -> bf16, transposed, padded (R9's)
__global__ void build_weights(const float* __restrict__ w_conv,
                              const float* __restrict__ W1,
                              const float* __restrict__ W2,
                              const float* __restrict__ W3,
                              unsigned short* __restrict__ ws) {
    const int idx = blockIdx.x * 256 + threadIdx.x;
    const int WEFF_T = 28 * KP1;
    if (idx < WEFF_T) {
        const int j4 = idx / KP1, p = idx % KP1;
        const int j = j4 * 4;
        float a0 = 0.f, a1 = 0.f, a2 = 0.f, a3 = 0.f;
        if (p < 784 && j4 < 25) {
            const int y = p / 28, xx = p % 28;
#pragma unroll
            for (int ky = 0; ky < 3; ++ky) {
                const int py = y - ky;
                if (py < 0 || py >= 26) continue;
#pragma unroll
                for (int kx = 0; kx < 3; ++kx) {
                    const int px = xx - kx;
                    if (px < 0 || px >= 26) continue;
                    const float wc = w_conv[ky * 3 + kx];
                    const float4 w = *reinterpret_cast<const float4*>(
                        W1 + (size_t)(py * 26 + px) * 100 + j);
                    a0 = fmaf(wc, w.x, a0); a1 = fmaf(wc, w.y, a1);
                    a2 = fmaf(wc, w.z, a2); a3 = fmaf(wc, w.w, a3);
                }
            }
        }
        ws[(size_t)(j + 0) * KP1 + p] = f2bf(a0);
        ws[(size_t)(j + 1) * KP1 + p] = f2bf(a1);
        ws[(size_t)(j + 2) * KP1 + p] = f2bf(a2);
        ws[(size_t)(j + 3) * KP1 + p] = f2bf(a3);
    } else if (idx < WEFF_T + NP * K2P) {
        const int r = idx - WEFF_T;
        const int col = r / K2P, k = r % K2P;
        float v = (col < 100 && k < 100) ? W2[k * 100 + col] : 0.f;
        ws[W2T_OFF + r] = f2bf(v);
    } else if (idx < WEFF_T + NP * K2P + 16 * K2P) {
        const int r = idx - WEFF_T - NP * K2P;
        const int col = r / K2P, k = r % K2P;
        float v = (col < 10 && k < 100) ? W3[k * 10 + col] : 0.f;
        ws[W3T_OFF + r] = f2bf(v);
    }
}

// ---------------- Kernel B: fused, zero-barrier
__global__ __launch_bounds__(NT, 1)
void fused(const float* __restrict__ x,
           const unsigned short* __restrict__ wst,
           const float* __restrict__ b1,
           const float* __restrict__ b2,
           const float* __restrict__ b3,
           float* __restrict__ out) {
    __shared__ __attribute__((aligned(16))) unsigned short xb[BM][XC];   // 53760 B
    __shared__ __attribute__((aligned(16))) unsigned short h1[BM][136];  //  8704 B
    __shared__ __attribute__((aligned(16))) unsigned short h2[BM][136];  //  8704 B

    const int tid  = threadIdx.x;
    const int lane = tid & 63;
    const int wv   = tid >> 6;           // 0..1; wave owns rows wv*16..+15
    const int l15  = lane & 15;
    const int lk   = lane >> 4;          // 0..3
    const int wr   = wv * 16;
    const size_t b0 = (size_t)blockIdx.x * BM;

    const unsigned short* weff = wst;
    const unsigned short* w2t  = wst + W2T_OFF;
    const unsigned short* w3t  = wst + W3T_OFF;

    // ---- zero own pads: xb cols 832..839 unread; zero cols 784..831 (swizzled)
    //      and h1/h2 k-pad cols 100..127 (own rows). Same-wave, no sync needed.
    for (int f = lane; f < 16 * 24; f += 64) {       // 48 ushort pad = 24 u32/row
        const int r = wr + f / 24;
        const int cw = 392 + (f % 24);               // word index 392..415
        const int sw = cw ^ ((r & 7) << 2);
        *reinterpret_cast<unsigned int*>((char*)&xb[0][0] + ((size_t)r * 420 + sw) * 4) = 0u;
    }
    for (int f = lane; f < 16 * 14; f += 64) {
        const int r = wr + f / 14, c = 100 + (f % 14) * 2;
        *reinterpret_cast<unsigned int*>(&h1[r][c]) = 0u;
        *reinterpret_cast<unsigned int*>(&h2[r][c]) = 0u;
    }

    // ---- copy own 16 rows of x (16x784 fp32 = 49 float4/lane), 12-deep batches
    {
        const float* xsrc = x + (b0 + wr) * 784;
        const int base = lane * 4;
        char* lb = (char*)&xb[0][0];
        auto wr_lds = [&](int it, float4 v) {
            const int F   = it * 256 + base;         // flat float idx in own region
            const int row = F / 784;                 // 0..15 (magic-mul div)
            const int col = F - row * 784;           // multiple of 4
            const int cw  = (col >> 1) ^ ((row & 7) << 2);
            *reinterpret_cast<uint2*>(lb + ((size_t)(wr + row) * 420 + cw) * 4) =
                (uint2){pkbf(v.x, v.y), pkbf(v.z, v.w)};
        };
        float4 v[12];
#pragma unroll 1
        for (int b = 0; b < 4; ++b) {
#pragma unroll
            for (int i = 0; i < 12; ++i)
                v[i] = *reinterpret_cast<const float4*>(xsrc + (b * 12 + i) * 256 + base);
            SBAR0;                                   // all 12 issued before use
#pragma unroll
            for (int i = 0; i < 12; ++i) wr_lds(b * 12 + i, v[i]);
            SBAR0;
        }
        float4 vt = *reinterpret_cast<const float4*>(xsrc + 48 * 256 + base);
        wr_lds(48, vt);
    }
    asm volatile("s_waitcnt vmcnt(0) lgkmcnt(0)" ::: "memory");
    SBAR0;   // own data fully in LDS; no barrier — other waves are independent

    // ---- GEMM1: 13 windows of K=64 (k 0..831 incl. zero pad; no tail)
    f32x4 acc[7];
#pragma unroll
    for (int n = 0; n < 7; ++n) acc[n] = (f32x4){0.f, 0.f, 0.f, 0.f};

    const int arow = wr + l15;
    const int swz  = (l15 & 7) << 2;                  // word-XOR
    const char* lb = (const char*)&xb[0][0];
    const unsigned aoff0 = ((unsigned)arow * 420 + ((lk * 4) ^ swz)) * 4;
    const unsigned aoff1 = ((unsigned)arow * 420 + ((16 + lk * 4) ^ swz)) * 4;

    const unsigned short* bp[7];
#pragma unroll
    for (int n = 0; n < 7; ++n)
        bp[n] = weff + (size_t)(n * 16 + l15) * KP1 + lk * 8;

    bf16x8 Bv[2][7][2];
    auto loadB = [&](int w, int buf) {
#pragma unroll
        for (int n = 0; n < 7; ++n) {
            Bv[buf][n][0] = *reinterpret_cast<const bf16x8*>(bp[n] + w * 64);
            Bv[buf][n][1] = *reinterpret_cast<const bf16x8*>(bp[n] + w * 64 + 32);
        }
    };

    loadB(0, 0);
#pragma unroll
    for (int w = 0; w < 13; ++w) {
        if (w < 12) loadB(w + 1, (w + 1) & 1);
        SBAR0;                                        // pin prefetch before compute
        const bf16x8 a0 = *reinterpret_cast<const bf16x8*>(lb + aoff0 + w * 128);
        const bf16x8 a1 = *reinterpret_cast<const bf16x8*>(lb + aoff1 + w * 128);
#pragma unroll
        for (int n = 0; n < 7; ++n)
            acc[n] = __builtin_amdgcn_mfma_f32_16x16x32_bf16(a0, Bv[w & 1][n][0], acc[n], 0, 0, 0);
#pragma unroll
        for (int n = 0; n < 7; ++n)
            acc[n] = __builtin_amdgcn_mfma_f32_16x16x32_bf16(a1, Bv[w & 1][n][1], acc[n], 0, 0, 0);
        SBAR0;
    }

    // ---- h1 = relu(acc + b1) -> LDS (own rows)
    float bias[7];
#pragma unroll
    for (int n = 0; n < 7; ++n) {
        const int c = n * 16 + l15;
        bias[n] = (c < 100) ? b1[c] : 0.f;
    }
#pragma unroll
    for (int n = 0; n < 7; ++n) {
        const int col = n * 16 + l15;
        if (col < 100)
#pragma unroll
            for (int q = 0; q < 4; ++q)
                h1[wr + lk * 4 + q][col] = f2bf(fmaxf(acc[n][q] + bias[n], 0.f));
    }
    asm volatile("s_waitcnt lgkmcnt(0)" ::: "memory");
    SBAR0;

    // ---- GEMM2: h2 = relu(h1 @ W2 + b2); B d1-prefetched from L2
    f32x4 acc2[7];
#pragma unroll
    for (int n = 0; n < 7; ++n) acc2[n] = (f32x4){0.f, 0.f, 0.f, 0.f};
    bf16x8 B2[2][7];
    auto loadB2 = [&](int ks, int buf) {
#pragma unroll
        for (int n = 0; n < 7; ++n)
            B2[buf][n] = *reinterpret_cast<const bf16x8*>(
                w2t + (size_t)(n * 16 + l15) * K2P + ks * 32 + lk * 8);
    };
    loadB2(0, 0);
#pragma unroll
    for (int ks = 0; ks < 4; ++ks) {
        if (ks < 3) loadB2(ks + 1, (ks + 1) & 1);
        SBAR0;
        const bf16x8 af = *reinterpret_cast<const bf16x8*>(&h1[wr + l15][ks * 32 + lk * 8]);
#pragma unroll
        for (int n = 0; n < 7; ++n)
            acc2[n] = __builtin_amdgcn_mfma_f32_16x16x32_bf16(af, B2[ks & 1][n], acc2[n], 0, 0, 0);
        SBAR0;
    }
#pragma unroll
    for (int n = 0; n < 7; ++n) {
        const int c = n * 16 + l15;
        bias[n] = (c < 100) ? b2[c] : 0.f;
    }
#pragma unroll
    for (int n = 0; n < 7; ++n) {
        const int col = n * 16 + l15;
        if (col < 100)
#pragma unroll
            for (int q = 0; q < 4; ++q)
                h2[wr + lk * 4 + q][col] = f2bf(fmaxf(acc2[n][q] + bias[n], 0.f));
    }
    asm volatile("s_waitcnt lgkmcnt(0)" ::: "memory");
    SBAR0;

    // ---- GEMM3: out = h2 @ W3 + b3 (own rows)
    f32x4 acc3 = (f32x4){0.f, 0.f, 0.f, 0.f};
#pragma unroll
    for (int ks = 0; ks < 4; ++ks) {
        const bf16x8 bfr = *reinterpret_cast<const bf16x8*>(
            w3t + (size_t)l15 * K2P + ks * 32 + lk * 8);
        const bf16x8 af = *reinterpret_cast<const bf16x8*>(&h2[wr + l15][ks * 32 + lk * 8]);
        acc3 = __builtin_amdgcn_mfma_f32_16x16x32_bf16(af, bfr, acc3, 0, 0, 0);
    }
    if (l15 < 10) {
        const float bb = b3[l15];
#pragma unroll
        for (int q = 0; q < 4; ++q) {
            const size_t row = b0 + wr + lk * 4 + q;
            out[row * 10 + l15] = acc3[q] + bb;
        }
    }
}

extern "C" void kernel_launch(void* const* d_in, const int* in_sizes, int n_in,
                              void* d_out, int out_size, void* d_ws, size_t ws_size,
                              hipStream_t stream) {
    const float* x      = (const float*)d_in[0];
    const float* w_conv = (const float*)d_in[1];
    const float* W1     = (const float*)d_in[2];
    const float* b1     = (const float*)d_in[3];
    const float* W2     = (const float*)d_in[4];
    const float* b2     = (const float*)d_in[5];
    const float* W3     = (const float*)d_in[6];
    const float* b3     = (const float*)d_in[7];
    float* out = (float*)d_out;
    unsigned short* ws = (unsigned short*)d_ws;

    const int total = 28 * KP1 + NP * K2P + 16 * K2P;   // 39680
    build_weights<<<(total + 255) / 256, 256, 0, stream>>>(w_conv, W1, W2, W3, ws);
    fused<<<32768 / BM, NT, 0, stream>>>(x, ws, b1, b2, b3, out);
}

// Round 12
// 71.108 us; speedup vs baseline: 1.0542x; 1.0542x over previous
//
#include <hip/hip_runtime.h>

// R12: R10 producer/consumer + DEEP-BATCHED copy (the one change).
//   Little's law audit showed every prior round held <4KB/CU of x-loads in
//   flight -> 0.6-1.7 TB/s effective. Copy waves now issue 13 (12) 1KB
//   wave-loads back-to-back (sched_barrier-pinned), ~50KB/CU in flight,
//   then drain through cvt_pk+ds_write. Compute waves unchanged from R10.

typedef __attribute__((ext_vector_type(8))) short bf16x8;
typedef __attribute__((ext_vector_type(4))) float f32x4;

#define KP1 832     // Weff K padded (784 -> 13*64)
#define NP  112     // hidden N padded (100 -> 7*16)
#define K2P 128     // GEMM2/3 K padded
#define NT  512
#define TILES 4
#define ROWS 32
#define XC  840     // ushorts per xs row (832 data + 8 pad)

#define W2T_OFF (NP * KP1)              // 93184
#define W3T_OFF (W2T_OFF + NP * K2P)    // 107520

#define SBAR0 __builtin_amdgcn_sched_barrier(0)

__device__ __forceinline__ unsigned short f2bf(float f) {
    unsigned int u = __float_as_uint(f);
    u += 0x7FFFu + ((u >> 16) & 1u);    // RNE
    return (unsigned short)(u >> 16);
}

__device__ __forceinline__ unsigned int pkbf(float a, float b) {
    unsigned int r;
    asm("v_cvt_pk_bf16_f32 %0, %1, %2" : "=v"(r) : "v"(a), "v"(b));
    return r;
}

// ---------------- Kernel A: weights -> bf16, transposed, padded (R9's)
__global__ void build_weights(const float* __restrict__ w_conv,
                              const float* __restrict__ W1,
                              const float* __restrict__ W2,
                              const float* __restrict__ W3,
                              unsigned short* __restrict__ ws) {
    const int idx = blockIdx.x * 256 + threadIdx.x;
    const int WEFF_T = 28 * KP1;
    if (idx < WEFF_T) {
        const int j4 = idx / KP1, p = idx % KP1;
        const int j = j4 * 4;
        float a0 = 0.f, a1 = 0.f, a2 = 0.f, a3 = 0.f;
        if (p < 784 && j4 < 25) {
            const int y = p / 28, xx = p % 28;
#pragma unroll
            for (int ky = 0; ky < 3; ++ky) {
                const int py = y - ky;
                if (py < 0 || py >= 26) continue;
#pragma unroll
                for (int kx = 0; kx < 3; ++kx) {
                    const int px = xx - kx;
                    if (px < 0 || px >= 26) continue;
                    const float wc = w_conv[ky * 3 + kx];
                    const float4 w = *reinterpret_cast<const float4*>(
                        W1 + (size_t)(py * 26 + px) * 100 + j);
                    a0 = fmaf(wc, w.x, a0); a1 = fmaf(wc, w.y, a1);
                    a2 = fmaf(wc, w.z, a2); a3 = fmaf(wc, w.w, a3);
                }
            }
        }
        ws[(size_t)(j + 0) * KP1 + p] = f2bf(a0);
        ws[(size_t)(j + 1) * KP1 + p] = f2bf(a1);
        ws[(size_t)(j + 2) * KP1 + p] = f2bf(a2);
        ws[(size_t)(j + 3) * KP1 + p] = f2bf(a3);
    } else if (idx < WEFF_T + NP * K2P) {
        const int r = idx - WEFF_T;
        const int col = r / K2P, k = r % K2P;
        float v = (col < 100 && k < 100) ? W2[k * 100 + col] : 0.f;
        ws[W2T_OFF + r] = f2bf(v);
    } else if (idx < WEFF_T + NP * K2P + 16 * K2P) {
        const int r = idx - WEFF_T - NP * K2P;
        const int col = r / K2P, k = r % K2P;
        float v = (col < 10 && k < 100) ? W3[k * 10 + col] : 0.f;
        ws[W3T_OFF + r] = f2bf(v);
    }
}

// ---------------- Kernel B: fused, producer/consumer, deep copy
__global__ __launch_bounds__(NT, 2)
void fused(const float* __restrict__ x,
           const unsigned short* __restrict__ wst,
           const float* __restrict__ b1,
           const float* __restrict__ b2,
           const float* __restrict__ b3,
           float* __restrict__ out) {
    __shared__ __attribute__((aligned(16))) unsigned short xs[2][ROWS][XC]; // 107520 B
    __shared__ __attribute__((aligned(16))) unsigned short h1[ROWS][136];   // 8704 B
    __shared__ __attribute__((aligned(16))) unsigned short h2[ROWS][136];   // 8704 B

    const int tid  = threadIdx.x;
    const int lane = tid & 63;
    const int wv   = tid >> 6;            // 0..7
    const bool is_copy = (wv >= 4);
    const int l15  = lane & 15;
    const int lk   = lane >> 4;           // 0..3
    const int wv_m = (wv >> 1) & 1;       // compute: row half
    const int wv_n = wv & 1;              // compute: frag half
    const int wr   = wv_m * 16;
    const int nb   = wv_n * 4;            // frags nb..min(nb+3,6)
    const size_t b0 = (size_t)blockIdx.x * (TILES * ROWS);

    const unsigned short* weff = wst;
    const unsigned short* w2t  = wst + W2T_OFF;
    const unsigned short* w3t  = wst + W3T_OFF;

    // ---- prologue: zero xs col-pads (784..831, both bufs) and h k-pads
    for (int i = tid; i < 1536; i += NT) {
        const int buf = i / 768, r = (i % 768) / 24, c = (i % 768) % 24;
        *reinterpret_cast<unsigned int*>(&xs[buf][r][784 + c * 2]) = 0u;
    }
    for (int i = tid; i < 1152; i += NT) {
        const int a = i / 576, r = (i % 576) / 18, c = (i % 576) % 18;
        unsigned short* hp = a ? &h2[0][0] : &h1[0][0];
        *reinterpret_cast<unsigned int*>(hp + r * 136 + 100 + c * 2) = 0u;
    }
    // ---- prologue: all 512 threads copy tile 0 — DEEP batch (13 loads first)
    {
        const float* src = x + b0 * 784;
        float4 v[13];
#pragma unroll
        for (int i = 0; i < 13; ++i) {
            const int f = i * 2048 + tid * 4;
            v[i] = (f < ROWS * 784) ? *reinterpret_cast<const float4*>(src + f)
                                    : (float4){0.f, 0.f, 0.f, 0.f};
        }
        SBAR0;                                        // all loads issued first
#pragma unroll
        for (int i = 0; i < 13; ++i) {
            const int f = i * 2048 + tid * 4;
            if (f < ROWS * 784) {
                const int row = f / 784, col = f - row * 784;
                *reinterpret_cast<uint2*>(&xs[0][row][col]) =
                    (uint2){pkbf(v[i].x, v[i].y), pkbf(v[i].z, v[i].w)};
            }
        }
    }
    __syncthreads();

    // compute-wave constants
    float bias1[4], bias2[4], bb3 = 0.f;
    const unsigned short* bp[4];
    if (!is_copy) {
#pragma unroll
        for (int j = 0; j < 4; ++j) {
            const int nf = nb + j, c = nf * 16 + l15;
            bias1[j] = (nf < 7 && c < 100) ? b1[c] : 0.f;
            bias2[j] = (nf < 7 && c < 100) ? b2[c] : 0.f;
            bp[j] = weff + (size_t)(nf * 16 + l15) * KP1;   // addr only; deref guarded
        }
        if (wv_n == 0 && l15 < 10) bb3 = b3[l15];
    }

    // DEEP copy half-tile: issue ALL loads back-to-back, fence, then drain.
    // i0/i1 are literals at both call sites -> static v[] indexing.
    auto copy_half = [&](int t1, int i0, int i1) {
        const int ctid = tid - 256;
        const float* src = x + (b0 + (size_t)t1 * ROWS) * 784;
        unsigned short* dst = &xs[t1 & 1][0][0];
        float4 v[13];
#pragma unroll
        for (int i = i0; i < i1; ++i) {
            const int f = i * 1024 + ctid * 4;
            v[i - i0] = (f < ROWS * 784)
                ? *reinterpret_cast<const float4*>(src + f)
                : (float4){0.f, 0.f, 0.f, 0.f};
        }
        SBAR0;                                        // ~13KB/wave in flight
#pragma unroll
        for (int i = i0; i < i1; ++i) {
            const int f = i * 1024 + ctid * 4;
            if (f < ROWS * 784) {
                const int row = f / 784, col = f - row * 784;
                *reinterpret_cast<uint2*>(dst + row * XC + col) =
                    (uint2){pkbf(v[i - i0].x, v[i - i0].y),
                            pkbf(v[i - i0].z, v[i - i0].w)};
            }
        }
    };

#pragma unroll 1
    for (int t = 0; t < TILES; ++t) {
        const unsigned short* xb = &xs[t & 1][0][0];

        // ======== phase A: copy first half of t+1  |  GEMM1(t) + h1
        if (is_copy) {
            if (t + 1 < TILES) copy_half(t + 1, 0, 13);
        } else {
            f32x4 acc[4];
#pragma unroll
            for (int j = 0; j < 4; ++j) acc[j] = (f32x4){0.f, 0.f, 0.f, 0.f};

            bf16x8 A[2][2];          // [buf][ks]
            bf16x8 Bv[2][4][2];      // [buf][frag][ks]
            const unsigned short* ap = xb + (wr + l15) * XC;

            auto loadW = [&](int w, int b) {
                A[b][0] = *reinterpret_cast<const bf16x8*>(ap + w * 64 + lk * 8);
                A[b][1] = *reinterpret_cast<const bf16x8*>(ap + w * 64 + 32 + lk * 8);
#pragma unroll
                for (int j = 0; j < 4; ++j)
                    if (nb + j < 7) {
                        Bv[b][j][0] = *reinterpret_cast<const bf16x8*>(bp[j] + w * 64 + lk * 8);
                        Bv[b][j][1] = *reinterpret_cast<const bf16x8*>(bp[j] + w * 64 + 32 + lk * 8);
                    }
            };
            loadW(0, 0);
#pragma unroll
            for (int w = 0; w < 13; ++w) {
                if (w < 12) loadW(w + 1, (w + 1) & 1);
                SBAR0;
#pragma unroll
                for (int ks = 0; ks < 2; ++ks)
#pragma unroll
                    for (int j = 0; j < 4; ++j)
                        if (nb + j < 7)
                            acc[j] = __builtin_amdgcn_mfma_f32_16x16x32_bf16(
                                A[w & 1][ks], Bv[w & 1][j][ks], acc[j], 0, 0, 0);
                SBAR0;
            }
            // h1 = relu(acc + b1)
#pragma unroll
            for (int j = 0; j < 4; ++j) {
                const int nf = nb + j, col = nf * 16 + l15;
                if (nf < 7 && col < 100)
#pragma unroll
                    for (int q = 0; q < 4; ++q)
                        h1[wr + lk * 4 + q][col] = f2bf(fmaxf(acc[j][q] + bias1[j], 0.f));
            }
        }
        __syncthreads();

        // ======== phase B: copy second half of t+1  |  GEMM2 + h2
        if (is_copy) {
            if (t + 1 < TILES) copy_half(t + 1, 13, 25);
        } else {
            f32x4 acc2[4];
#pragma unroll
            for (int j = 0; j < 4; ++j) acc2[j] = (f32x4){0.f, 0.f, 0.f, 0.f};
#pragma unroll
            for (int ks = 0; ks < 4; ++ks) {
                const int kb = ks * 32 + lk * 8;
                const bf16x8 af = *reinterpret_cast<const bf16x8*>(&h1[wr + l15][kb]);
#pragma unroll
                for (int j = 0; j < 4; ++j) {
                    const int nf = nb + j;
                    if (nf < 7) {
                        const bf16x8 bfr = *reinterpret_cast<const bf16x8*>(
                            w2t + (size_t)(nf * 16 + l15) * K2P + kb);
                        acc2[j] = __builtin_amdgcn_mfma_f32_16x16x32_bf16(af, bfr, acc2[j], 0, 0, 0);
                    }
                }
            }
#pragma unroll
            for (int j = 0; j < 4; ++j) {
                const int nf = nb + j, col = nf * 16 + l15;
                if (nf < 7 && col < 100)
#pragma unroll
                    for (int q = 0; q < 4; ++q)
                        h2[wr + lk * 4 + q][col] = f2bf(fmaxf(acc2[j][q] + bias2[j], 0.f));
            }
        }
        __syncthreads();

        // ======== phase C (no barrier): GEMM3 + store by wv_n==0 computers
        if (!is_copy && wv_n == 0) {
            f32x4 acc3 = (f32x4){0.f, 0.f, 0.f, 0.f};
#pragma unroll
            for (int ks = 0; ks < 4; ++ks) {
                const int kb = ks * 32 + lk * 8;
                const bf16x8 bfr = *reinterpret_cast<const bf16x8*>(
                    w3t + (size_t)l15 * K2P + kb);
                const bf16x8 af = *reinterpret_cast<const bf16x8*>(&h2[wr + l15][kb]);
                acc3 = __builtin_amdgcn_mfma_f32_16x16x32_bf16(af, bfr, acc3, 0, 0, 0);
            }
            if (l15 < 10) {
#pragma unroll
                for (int q = 0; q < 4; ++q) {
                    const size_t row = b0 + (size_t)t * ROWS + wr + lk * 4 + q;
                    out[row * 10 + l15] = acc3[q] + bb3;
                }
            }
        }
    }
}

extern "C" void kernel_launch(void* const* d_in, const int* in_sizes, int n_in,
                              void* d_out, int out_size, void* d_ws, size_t ws_size,
                              hipStream_t stream) {
    const float* x      = (const float*)d_in[0];
    const float* w_conv = (const float*)d_in[1];
    const float* W1     = (const float*)d_in[2];
    const float* b1     = (const float*)d_in[3];
    const float* W2     = (const float*)d_in[4];
    const float* b2     = (const float*)d_in[5];
    const float* W3     = (const float*)d_in[6];
    const float* b3     = (const float*)d_in[7];
    float* out = (float*)d_out;
    unsigned short* ws = (unsigned short*)d_ws;

    const int total = 28 * KP1 + NP * K2P + 16 * K2P;   // 39680
    build_weights<<<(total + 255) / 256, 256, 0, stream>>>(w_conv, W1, W2, W3, ws);
    fused<<<32768 / (TILES * ROWS), NT, 0, stream>>>(x, ws, b1, b2, b3, out);
}

// Round 13
// 33.106 us; speedup vs baseline: 2.2643x; 2.1479x over previous
//
#include <hip/hip_runtime.h>

// R13: traffic-minimized fused conv+MLP (the wall is L3 BW ~7 TB/s on TOTAL
//   traffic, fit across R4/R6/R9/R10 exactly).
//   x 103MB (irreducible) + B 54MB (BM=128, staged per block) + W2 7MB
//   (LDS-staged once per block) ~= 166MB -> ~24us.
//   x: reg-staged fp32->bf16 (cvt_pk) into [128][72] LDS (2-way banks);
//   B: gload_lds with XOR source swizzle (R9's proven scheme);
//   13 uniform K-stages, counted vmcnt, race-free dbuf rotation
//   (B(t+1) issued only after the barrier retiring bs[(t+1)&1] readers).

typedef __attribute__((ext_vector_type(8))) short bf16x8;
typedef __attribute__((ext_vector_type(4))) float f32x4;

#define KP1 832
#define NPB 128     // weff rows padded (uniform B staging)
#define NP  112
#define K2P 128
#define BM  128
#define NT  512

#define W2T_OFF (NPB * KP1)             // 106496
#define W3T_OFF (W2T_OFF + NP * K2P)    // 120832
#define WS_TOTAL (W3T_OFF + 16 * K2P)   // 122880 ushorts

#define SBAR0 __builtin_amdgcn_sched_barrier(0)
#define BAR   __builtin_amdgcn_s_barrier()
#define WAITV(N) asm volatile("s_waitcnt vmcnt(" #N ")" ::: "memory")
#define WAITL    asm volatile("s_waitcnt lgkmcnt(0)" ::: "memory")

__device__ __forceinline__ unsigned short f2bf(float f) {
    unsigned int u = __float_as_uint(f);
    u += 0x7FFFu + ((u >> 16) & 1u);    // RNE
    return (unsigned short)(u >> 16);
}

__device__ __forceinline__ unsigned int pkbf(float a, float b) {
    unsigned int r;
    asm("v_cvt_pk_bf16_f32 %0, %1, %2" : "=v"(r) : "v"(a), "v"(b));
    return r;
}

__device__ __forceinline__ void gload_lds16(const void* g, void* l) {
    __builtin_amdgcn_global_load_lds(
        (const __attribute__((address_space(1))) unsigned int*)g,
        (__attribute__((address_space(3))) unsigned int*)l, 16, 0, 0);
}

// ---------------- Kernel A: weights -> bf16, transposed, padded (128-row weff)
__global__ void build_weights(const float* __restrict__ w_conv,
                              const float* __restrict__ W1,
                              const float* __restrict__ W2,
                              const float* __restrict__ W3,
                              unsigned short* __restrict__ ws) {
    const int idx = blockIdx.x * 256 + threadIdx.x;
    const int WEFF_T = 32 * KP1;                 // 32 j-quads (128 rows)
    if (idx < WEFF_T) {
        const int j4 = idx / KP1, p = idx % KP1;
        const int j = j4 * 4;
        float a0 = 0.f, a1 = 0.f, a2 = 0.f, a3 = 0.f;
        if (p < 784 && j4 < 25) {
            const int y = p / 28, xx = p % 28;
#pragma unroll
            for (int ky = 0; ky < 3; ++ky) {
                const int py = y - ky;
                if (py < 0 || py >= 26) continue;
#pragma unroll
                for (int kx = 0; kx < 3; ++kx) {
                    const int px = xx - kx;
                    if (px < 0 || px >= 26) continue;
                    const float wc = w_conv[ky * 3 + kx];
                    const float4 w = *reinterpret_cast<const float4*>(
                        W1 + (size_t)(py * 26 + px) * 100 + j);
                    a0 = fmaf(wc, w.x, a0); a1 = fmaf(wc, w.y, a1);
                    a2 = fmaf(wc, w.z, a2); a3 = fmaf(wc, w.w, a3);
                }
            }
        }
        ws[(size_t)(j + 0) * KP1 + p] = f2bf(a0);
        ws[(size_t)(j + 1) * KP1 + p] = f2bf(a1);
        ws[(size_t)(j + 2) * KP1 + p] = f2bf(a2);
        ws[(size_t)(j + 3) * KP1 + p] = f2bf(a3);
    } else if (idx < WEFF_T + NP * K2P) {
        const int r = idx - WEFF_T;
        const int col = r / K2P, k = r % K2P;
        float v = (col < 100 && k < 100) ? W2[k * 100 + col] : 0.f;
        ws[W2T_OFF + r] = f2bf(v);
    } else if (idx < WEFF_T + NP * K2P + 16 * K2P) {
        const int r = idx - WEFF_T - NP * K2P;
        const int col = r / K2P, k = r % K2P;
        float v = (col < 10 && k < 100) ? W3[k * 10 + col] : 0.f;
        ws[W3T_OFF + r] = f2bf(v);
    }
}

// ---------------- Kernel B: fused
union SMem {
    struct {
        unsigned short xs[2][BM][72];    // 36864 B (bf16, 2-way banks)
        unsigned short bs[2][NPB][64];   // 32768 B (gload_lds, XOR-swizzled)
    } g1;                                 // 69632 B
    struct {
        unsigned short h1[BM][136];      // 34816 B
        union {
            unsigned short w2s[NP][136]; // 30464 B (dead before h2 written)
            unsigned short h2[BM][136];  // 34816 B
        } u;
    } g2;                                 // 69632 B
};

__global__ __launch_bounds__(NT, 2)
void fused(const float* __restrict__ x,
           const unsigned short* __restrict__ wst,
           const float* __restrict__ b1,
           const float* __restrict__ b2,
           const float* __restrict__ b3,
           float* __restrict__ out) {
    __shared__ SMem sm;
    const int tid  = threadIdx.x;
    const int lane = tid & 63;
    const int wv   = tid >> 6;        // 0..7
    const int wv_m = wv >> 1;         // 0..3 -> rows wv_m*32 (2 m-frags)
    const int wv_n = wv & 1;          // 0..1 -> frags wv_n*4..(+3|+2)
    const int l15  = lane & 15;
    const int lk   = lane >> 4;       // 0..3
    const int wrow = wv_m * 32;
    const int nb   = wv_n * 4;
    const size_t b0 = (size_t)blockIdx.x * BM;

    const unsigned short* weff = wst;
    const unsigned short* w2t  = wst + W2T_OFF;
    const unsigned short* w3t  = wst + W3T_OFF;

    // x staging map: idx=q*512+tid -> row=idx>>4 (xrow+q*32), chunk=idx&15
    const int xrow = tid >> 4;
    const int xch  = tid & 15;
    const float* xbase = x + (b0 + xrow) * 784 + xch * 4;

    f32x4 acc[2][4];
#pragma unroll
    for (int m = 0; m < 2; ++m)
#pragma unroll
        for (int j = 0; j < 4; ++j) acc[m][j] = (f32x4){0.f, 0.f, 0.f, 0.f};

    float4 xv[4];
    auto issueX = [&](int kt) {
#pragma unroll
        for (int q = 0; q < 4; ++q) {
            if (kt < 12 || xch < 4)   // stage 12: cols>=784 are pad
                xv[q] = *reinterpret_cast<const float4*>(xbase + (size_t)q * 32 * 784 + kt * 64);
            else
                xv[q] = (float4){0.f, 0.f, 0.f, 0.f};
        }
    };
    auto writeX = [&](int buf) {
        char* xp = (char*)&sm.g1.xs[buf][0][0];
#pragma unroll
        for (int q = 0; q < 4; ++q) {
            const uint2 w = {pkbf(xv[q].x, xv[q].y), pkbf(xv[q].z, xv[q].w)};
            *reinterpret_cast<uint2*>(xp + (xrow + q * 32) * 144 + xch * 8) = w;
        }
    };
    auto issueB = [&](int kt, int buf) {   // 2 gloads/wave: groups wv, wv+8
#pragma unroll
        for (int q = 0; q < 2; ++q) {
            const int g  = wv + 8 * q;
            const int rg = g * 8 + (lane >> 3);
            const int ch = (lane & 7) ^ (lane >> 3);       // inverse swizzle
            gload_lds16((const char*)weff + (size_t)rg * KP1 * 2 + kt * 128 + ch * 16,
                        &sm.g1.bs[buf][g * 8][0]);
        }
    };
    auto computeStage = [&](int buf) {
        const char* xp = (const char*)&sm.g1.xs[buf][0][0];
        const char* bp = (const char*)&sm.g1.bs[buf][0][0];
#pragma unroll
        for (int kh = 0; kh < 2; ++kh) {
            bf16x8 a[2];
#pragma unroll
            for (int m = 0; m < 2; ++m)
                a[m] = *reinterpret_cast<const bf16x8*>(
                    xp + (wrow + m * 16 + l15) * 144 + kh * 64 + lk * 16);
#pragma unroll
            for (int j = 0; j < 4; ++j) {
                const int nf = nb + j;
                if (nf < 7) {
                    const int rn = nf * 16 + l15;
                    const bf16x8 b = *reinterpret_cast<const bf16x8*>(
                        bp + rn * 128 + ((kh * 64 + lk * 16) ^ ((rn & 7) << 4)));
#pragma unroll
                    for (int m = 0; m < 2; ++m)
                        acc[m][j] = __builtin_amdgcn_mfma_f32_16x16x32_bf16(
                            a[m], b, acc[m][j], 0, 0, 0);
                }
            }
        }
    };

    // ---- GEMM1 prologue
    issueX(0); SBAR0;
    issueB(0, 0); SBAR0;
    WAITV(2); SBAR0;              // x(0) landed (B(0) in flight)
    writeX(0); SBAR0;
    issueX(1); SBAR0;             // outstanding: B(0)2 + x(1)4
    WAITV(4);                     // B(0) landed
    WAITL; BAR;

    // ---- GEMM1: 13 stages; entering t: xs/bs[t&1] ready, x(t+1) in flight
#pragma unroll
    for (int t = 0; t < 13; ++t) {
        if (t < 12) { issueB(t + 1, (t + 1) & 1); SBAR0; }   // buf retired at barrier(t-1)
        computeStage(t & 1);
        if (t == 12) break;
        WAITV(2); SBAR0;          // x(t+1) landed (B(t+1) in flight)
        writeX((t + 1) & 1); SBAR0;
        if (t < 11) { issueX(t + 2); SBAR0; WAITV(4); }      // B(t+1) landed
        else        { WAITV(0); }                             // drain B(12)
        WAITL; BAR;
    }
    __syncthreads();   // all g1 reads done -> g2 alias safe

    // ---- h1 = relu(acc+b1); h1 k-pad; stage W2 -> LDS
    {
        float bias[4];
#pragma unroll
        for (int j = 0; j < 4; ++j) {
            const int c = (nb + j) * 16 + l15;
            bias[j] = (nb + j < 7 && c < 100) ? b1[c] : 0.f;
        }
#pragma unroll
        for (int j = 0; j < 4; ++j) {
            const int nf = nb + j, col = nf * 16 + l15;
            if (nf < 7 && col < 100)
#pragma unroll
                for (int m = 0; m < 2; ++m)
#pragma unroll
                    for (int q = 0; q < 4; ++q)
                        sm.g2.h1[wrow + m * 16 + lk * 4 + q][col] =
                            f2bf(fmaxf(acc[m][j][q] + bias[j], 0.f));
        }
        if (wv_n == 1) {   // zero h1 pad cols 100..127 for rows wrow..wrow+31
            for (int f = lane; f < 32 * 14; f += 64) {
                const int r = wrow + f / 14, c = 100 + (f % 14) * 2;
                *reinterpret_cast<unsigned int*>(&sm.g2.h1[r][c]) = 0u;
            }
        }
#pragma unroll
        for (int q = 0; q < 4; ++q) {   // w2s[112][136] <- w2t (1792 chunks)
            const int idx = q * NT + tid;
            if (idx < 1792) {
                const int row = idx >> 4, ch = idx & 15;
                *reinterpret_cast<bf16x8*>(&sm.g2.u.w2s[row][ch * 8]) =
                    *reinterpret_cast<const bf16x8*>(w2t + row * K2P + ch * 8);
            }
        }
    }
    __syncthreads();

    // ---- GEMM2
    f32x4 acc2[2][4];
#pragma unroll
    for (int m = 0; m < 2; ++m)
#pragma unroll
        for (int j = 0; j < 4; ++j) acc2[m][j] = (f32x4){0.f, 0.f, 0.f, 0.f};
#pragma unroll
    for (int ks = 0; ks < 4; ++ks) {
        const int kb = ks * 32 + lk * 8;
        bf16x8 a[2];
#pragma unroll
        for (int m = 0; m < 2; ++m)
            a[m] = *reinterpret_cast<const bf16x8*>(&sm.g2.h1[wrow + m * 16 + l15][kb]);
#pragma unroll
        for (int j = 0; j < 4; ++j) {
            const int nf = nb + j;
            if (nf < 7) {
                const bf16x8 b = *reinterpret_cast<const bf16x8*>(
                    &sm.g2.u.w2s[nf * 16 + l15][kb]);
#pragma unroll
                for (int m = 0; m < 2; ++m)
                    acc2[m][j] = __builtin_amdgcn_mfma_f32_16x16x32_bf16(
                        a[m], b, acc2[m][j], 0, 0, 0);
            }
        }
    }
    __syncthreads();   // w2s reads done before h2 overwrites it

    // ---- h2 = relu(acc2+b2)
    {
        float bias[4];
#pragma unroll
        for (int j = 0; j < 4; ++j) {
            const int c = (nb + j) * 16 + l15;
            bias[j] = (nb + j < 7 && c < 100) ? b2[c] : 0.f;
        }
#pragma unroll
        for (int j = 0; j < 4; ++j) {
            const int nf = nb + j, col = nf * 16 + l15;
            if (nf < 7 && col < 100)
#pragma unroll
                for (int m = 0; m < 2; ++m)
#pragma unroll
                    for (int q = 0; q < 4; ++q)
                        sm.g2.u.h2[wrow + m * 16 + lk * 4 + q][col] =
                            f2bf(fmaxf(acc2[m][j][q] + bias[j], 0.f));
        }
        if (wv_n == 1) {
            for (int f = lane; f < 32 * 14; f += 64) {
                const int r = wrow + f / 14, c = 100 + (f % 14) * 2;
                *reinterpret_cast<unsigned int*>(&sm.g2.u.h2[r][c]) = 0u;
            }
        }
    }
    __syncthreads();

    // ---- GEMM3 (wv_n==0 waves): out = h2 @ W3 + b3  (w3t 4KB, L2-hot)
    if (wv_n == 0) {
        f32x4 acc3[2] = {(f32x4){0.f,0.f,0.f,0.f}, (f32x4){0.f,0.f,0.f,0.f}};
#pragma unroll
        for (int ks = 0; ks < 4; ++ks) {
            const int kb = ks * 32 + lk * 8;
            const bf16x8 b = *reinterpret_cast<const bf16x8*>(w3t + l15 * K2P + kb);
#pragma unroll
            for (int m = 0; m < 2; ++m) {
                const bf16x8 a = *reinterpret_cast<const bf16x8*>(
                    &sm.g2.u.h2[wrow + m * 16 + l15][kb]);
                acc3[m] = __builtin_amdgcn_mfma_f32_16x16x32_bf16(a, b, acc3[m], 0, 0, 0);
            }
        }
        if (l15 < 10) {
            const float bb = b3[l15];
#pragma unroll
            for (int m = 0; m < 2; ++m)
#pragma unroll
                for (int q = 0; q < 4; ++q) {
                    const size_t row = b0 + wrow + m * 16 + lk * 4 + q;
                    out[row * 10 + l15] = acc3[m][q] + bb;
                }
        }
    }
}

extern "C" void kernel_launch(void* const* d_in, const int* in_sizes, int n_in,
                              void* d_out, int out_size, void* d_ws, size_t ws_size,
                              hipStream_t stream) {
    const float* x      = (const float*)d_in[0];
    const float* w_conv = (const float*)d_in[1];
    const float* W1     = (const float*)d_in[2];
    const float* b1     = (const float*)d_in[3];
    const float* W2     = (const float*)d_in[4];
    const float* b2     = (const float*)d_in[5];
    const float* W3     = (const float*)d_in[6];
    const float* b3     = (const float*)d_in[7];
    float* out = (float*)d_out;
    unsigned short* ws = (unsigned short*)d_ws;

    const int total = 32 * KP1 + NP * K2P + 16 * K2P;   // 43008
    build_weights<<<(total + 255) / 256, 256, 0, stream>>>(w_conv, W1, W2, W3, ws);
    fused<<<32768 / BM, NT, 0, stream>>>(x, ws, b1, b2, b3, out);
}